// Round 10
// baseline (405.575 us; speedup 1.0000x reference)
//
#include <hip/hip_runtime.h>

typedef unsigned short u16;
typedef unsigned int u32;
typedef unsigned long long u64;
typedef __attribute__((ext_vector_type(8))) short short8;
typedef __attribute__((ext_vector_type(4))) float f32x4;
typedef __attribute__((ext_vector_type(4))) int int4v;

constexpr int Bsz = 2, Ssz = 4096, Hn = 16, Dh = 128, HID = 2048;
constexpr int Cch = 128, NCh = 32;
constexpr float EPSf = 1e-6f;

#define MFMA16 __builtin_amdgcn_mfma_f32_16x16x32_bf16
#define VMW(N) asm volatile("s_waitcnt vmcnt(" #N ")" ::: "memory")

__device__ __forceinline__ float b2f(u16 u) {
  unsigned int i = ((unsigned int)u) << 16;
  return __builtin_bit_cast(float, i);
}
__device__ __forceinline__ u16 f2b(float f) {
  unsigned int i = __builtin_bit_cast(unsigned int, f);
  i += 0x7fffu + ((i >> 16) & 1u);   // round-to-nearest-even
  return (u16)(i >> 16);
}

// async global->LDS, 16 B per lane; LDS dest = wave-uniform base + lane*16.
__device__ __forceinline__ void gload_lds16(const u16* g, u16* l) {
  __builtin_amdgcn_global_load_lds(
      (const __attribute__((address_space(1))) u32*)g,
      (__attribute__((address_space(3))) u32*)l, 16, 0, 0);
}

// ---------------------------------------------------------------------------
// x f32 -> bf16 (streaming, vectorized)
// ---------------------------------------------------------------------------
__global__ __launch_bounds__(256) void cvt_bf16(const float* __restrict__ x,
                                                u16* __restrict__ xb)
{
  const size_t n8 = (size_t)Bsz * Ssz * HID / 8;
  for (size_t i = (size_t)blockIdx.x * 256 + threadIdx.x; i < n8;
       i += (size_t)gridDim.x * 256) {
    const f32x4 a = *(const f32x4*)&x[i * 8];
    const f32x4 b = *(const f32x4*)&x[i * 8 + 4];
    u16 tmp[8];
#pragma unroll
    for (int u = 0; u < 4; ++u) { tmp[u] = f2b(a[u]); tmp[u + 4] = f2b(b[u]); }
    *(int4v*)&xb[i * 8] = *(const int4v*)tmp;
  }
}

// ---------------------------------------------------------------------------
// Weight transpose+convert: W f32 [K][N] -> WT bf16 [N][K], 64x64 tiles.
// ---------------------------------------------------------------------------
__global__ __launch_bounds__(256) void transpose4(
    const float* __restrict__ A0, const float* __restrict__ A1,
    const float* __restrict__ A2, const float* __restrict__ A3,
    u16* __restrict__ T0, u16* __restrict__ T1,
    u16* __restrict__ T2, u16* __restrict__ T3)
{
  constexpr int N = HID, LDT = 72;
  const int z = blockIdx.z;
  const float* __restrict__ A = (z == 0) ? A0 : (z == 1) ? A1 : (z == 2) ? A2 : A3;
  u16* __restrict__ T = (z == 0) ? T0 : (z == 1) ? T1 : (z == 2) ? T2 : T3;
  __shared__ u16 lds[64 * LDT];
  const int t = threadIdx.x;
  const int i = t >> 3, j = (t & 7) * 8;
  const int r0 = blockIdx.y * 64, c0 = blockIdx.x * 64;
#pragma unroll
  for (int half = 0; half < 2; ++half) {
    const int r = i + half * 32;
    const f32x4 a = *(const f32x4*)&A[(size_t)(r0 + r) * N + c0 + j];
    const f32x4 b = *(const f32x4*)&A[(size_t)(r0 + r) * N + c0 + j + 4];
    u16 tmp[8];
#pragma unroll
    for (int u = 0; u < 4; ++u) { tmp[u] = f2b(a[u]); tmp[u + 4] = f2b(b[u]); }
    *(int4v*)&lds[r * LDT + j] = *(const int4v*)tmp;
  }
  __syncthreads();
#pragma unroll
  for (int half = 0; half < 2; ++half) {
    const int c = i + half * 32;
    u16 tmp[8];
#pragma unroll
    for (int u = 0; u < 8; ++u) tmp[u] = lds[(j + u) * LDT + c];
    *(int4v*)&T[(size_t)(c0 + c) * N + r0 + j] = *(const int4v*)tmp;
  }
}

// ---------------------------------------------------------------------------
// 2-block/CU 256x256 GEMM: A bf16 [M][K] x WT bf16 [N][K] + bias, optional
// elu(x)+1. BK=32, 2-buffer rotation (depth-1), 8 waves (2Mx4N), LDS 64 KiB
// dynamic: [buf2][A|B][256][32], slot-swizzled. 64 KiB + VGPR<=128 -> two
// blocks co-resident per CU, so the per-window barrier stall of one block is
// hidden by the other block's MFMAs (m114 overlap).
// ---------------------------------------------------------------------------
template <int OUTF32>
__global__ __launch_bounds__(512) void gemm2blk(
    const u16* __restrict__ A,
    const u16* __restrict__ W0T, const u16* __restrict__ W1T, const u16* __restrict__ W2T,
    const float* __restrict__ bb0, const float* __restrict__ bb1, const float* __restrict__ bb2,
    void* __restrict__ o0, void* __restrict__ o1, void* __restrict__ o2,
    int elu_mask)
{
  constexpr int K = HID, N = HID;
  extern __shared__ u16 lds[];             // 32768 elems = 64 KiB

  const int z = blockIdx.z;
  const u16* __restrict__ WT    = (z == 0) ? W0T : (z == 1) ? W1T : W2T;
  const float* __restrict__ bias = (z == 0) ? bb0 : (z == 1) ? bb1 : bb2;
  void* __restrict__ outv = (z == 0) ? o0 : (z == 1) ? o1 : o2;
  const bool elu = (elu_mask >> z) & 1;

  // 2-D XCD map: XCD k owns m-band of 4 m-tiles x all 8 n-tiles.
  const int lid = blockIdx.x + 8 * blockIdx.y;   // 256 blocks/slice
  const int k8 = lid & 7, j32 = lid >> 3;        // XCD, index within XCD
  const int m0 = (k8 * 4 + (j32 >> 3)) * 256;
  const int n0 = (j32 & 7) * 256;

  const int t = threadIdx.x, lane = t & 63, w = t >> 6;  // 8 waves
  const int wm = w >> 2, wn = w & 3;
  const int l15 = lane & 15, lg = lane >> 4;
  const int sl2 = (l15 >> 1) & 3;          // read-side swizzle key

  // staging: stored slot s holds global slot s ^ ((row>>1)&3).
  const int strow = lane >> 2;                              // 0..15
  const int stslot = (lane & 3) ^ ((lane >> 3) & 3);        // swizzled src slot
  const u16* gA = A  + (size_t)(m0 + w * 16 + strow) * K + stslot * 8;
  const u16* gB = WT + (size_t)(n0 + w * 16 + strow) * K + stslot * 8;

  // per-thread LDS read offsets (elems); buf b base = b*16384 (A), +8192 (B)
  const int aRow = (wm * 128 + l15) * 32 + ((lg ^ sl2) << 3);
  const int bRow = 8192 + (wn * 64 + l15) * 32 + ((lg ^ sl2) << 3);
  u16* const lw = &lds[w * 512];           // wave's staging base

  f32x4 acc[8][4] = {};
  short8 aF[8], bF[4];

  // stage one 32-k tile into buffer SB (4 gloads), advance gA/gB
#define STAGE4(SB) do {                                                       \
    gload_lds16(gA,                   lw + (SB)*16384);                       \
    gload_lds16(gA + (size_t)128*K,   lw + (SB)*16384 + 4096);                \
    gload_lds16(gB,                   lw + (SB)*16384 + 8192);                \
    gload_lds16(gB + (size_t)128*K,   lw + (SB)*16384 + 8192 + 4096);         \
    gA += 32; gB += 32;                                                       \
  } while (0)

  // window: vmcnt(0) (tile BUF's loads issued last window; other block hides
  // the residual), barrier, stage next tile into BUF^1, compute BUF.
#define WINDOW(BUF, PF) do {                                                  \
    VMW(0);                                                                   \
    __builtin_amdgcn_s_barrier();                                             \
    if (PF) STAGE4((BUF)^1);                                                  \
    _Pragma("unroll")                                                         \
    for (int i = 0; i < 8; ++i)                                               \
      aF[i] = *(const short8*)&lds[(BUF)*16384 + aRow + i*512];               \
    _Pragma("unroll")                                                         \
    for (int j = 0; j < 4; ++j)                                               \
      bF[j] = *(const short8*)&lds[(BUF)*16384 + bRow + j*512];               \
    __builtin_amdgcn_s_setprio(1);                                            \
    _Pragma("unroll")                                                         \
    for (int i = 0; i < 8; ++i) {                                             \
      acc[i][0] = MFMA16(aF[i], bF[0], acc[i][0], 0, 0, 0);                   \
      acc[i][1] = MFMA16(aF[i], bF[1], acc[i][1], 0, 0, 0);                   \
      acc[i][2] = MFMA16(aF[i], bF[2], acc[i][2], 0, 0, 0);                   \
      acc[i][3] = MFMA16(aF[i], bF[3], acc[i][3], 0, 0, 0);                   \
    }                                                                         \
    __builtin_amdgcn_s_setprio(0);                                            \
  } while (0)

  // prologue: stage tile 0 into buf0
  STAGE4(0);

  // 64 windows (K/32), unrolled x2 so buffer indices are compile-time
  for (int W = 0; W < 64; W += 2) {
    WINDOW(0, (W + 1) < 64);   // compute tile W,   stage tile W+1 -> buf1
    WINDOW(1, (W + 2) < 64);   // compute tile W+1, stage tile W+2 -> buf0
  }

  // epilogue
#pragma unroll
  for (int j = 0; j < 4; ++j) {
    const int col = n0 + wn * 64 + j * 16 + l15;
    const float bv = bias[col];
#pragma unroll
    for (int i = 0; i < 8; ++i) {
      const int row0 = m0 + wm * 128 + i * 16 + lg * 4;
#pragma unroll
      for (int r = 0; r < 4; ++r) {
        float v = acc[i][j][r] + bv;
        if (elu) v = (v > 0.0f) ? (v + 1.0f) : __expf(v);   // elu(x)+1
        if (OUTF32) ((float*)outv)[(size_t)(row0 + r) * N + col] = v;
        else        ((u16*)outv)[(size_t)(row0 + r) * N + col] = f2b(v);
      }
    }
  }
#undef STAGE4
#undef WINDOW
}

// ---------------------------------------------------------------------------
// Pass 1, per (b,n,h): kvT[e][d] = sum_c v[c,e]*kf[c,d];  ksum[d] = sum_c kf[c,d]
// ---------------------------------------------------------------------------
__global__ __launch_bounds__(256) void pass1_kv(
    const u16* __restrict__ KF, const u16* __restrict__ V,
    u16* __restrict__ KVT, float* __restrict__ KSUM)
{
  constexpr int LD = 136;
  __shared__ u16 lk[128 * LD];
  __shared__ u16 lv[128 * LD];
  __shared__ float kp[256];
  const int bnh = blockIdx.x;
  const int h = bnh % Hn, n = (bnh / Hn) % NCh, b = bnh / (Hn * NCh);
  const size_t rowbase = (size_t)(b * Ssz + n * Cch) * HID + h * Dh;
  const int t = threadIdx.x, lane = t & 63, w = t >> 6;
  const int wr = (w >> 1) * 64, wc = (w & 1) * 64;
  const int l15 = lane & 15, lg = lane >> 4;
  const int sr = t >> 4, sc = (t & 15) * 8;

#pragma unroll
  for (int rep = 0; rep < 8; ++rep) {
    const int r = rep * 16 + sr;
    *(int4v*)&lk[r * LD + sc] = *(const int4v*)&KF[rowbase + (size_t)r * HID + sc];
    *(int4v*)&lv[r * LD + sc] = *(const int4v*)&V[rowbase + (size_t)r * HID + sc];
  }
  __syncthreads();

  // ksum: 256 threads, each sums 64 rows for col (t&127)
  {
    const int col = t & 127, hf = t >> 7;
    float s = 0.0f;
    for (int c = hf * 64; c < hf * 64 + 64; ++c) s += b2f(lk[c * LD + col]);
    kp[t] = s;
  }
  __syncthreads();
  if (t < 128) KSUM[(size_t)bnh * Dh + t] = kp[t] + kp[t + 128];

  f32x4 acc[4][4] = {};
#pragma unroll
  for (int kk = 0; kk < 4; ++kk) {
    const int cb = kk * 32 + lg * 8;
    short8 aF[4], bF[4];
#pragma unroll
    for (int i = 0; i < 4; ++i) {           // A[e][c] = v[c][e]
      const int e = wr + i * 16 + l15;
      short8 a;
#pragma unroll
      for (int u = 0; u < 8; ++u) a[u] = (short)lv[(cb + u) * LD + e];
      aF[i] = a;
    }
#pragma unroll
    for (int j = 0; j < 4; ++j) {           // B[c][d] = kf[c][d]
      const int d = wc + j * 16 + l15;
      short8 bb;
#pragma unroll
      for (int u = 0; u < 8; ++u) bb[u] = (short)lk[(cb + u) * LD + d];
      bF[j] = bb;
    }
#pragma unroll
    for (int i = 0; i < 4; ++i)
#pragma unroll
      for (int j = 0; j < 4; ++j)
        acc[i][j] = MFMA16(aF[i], bF[j], acc[i][j], 0, 0, 0);
  }

  u16* __restrict__ outp = KVT + (size_t)bnh * (Dh * Dh);
#pragma unroll
  for (int i = 0; i < 4; ++i) {
    const int e0 = wr + i * 16 + lg * 4;
#pragma unroll
    for (int j = 0; j < 4; ++j) {
      const int d = wc + j * 16 + l15;
#pragma unroll
      for (int r = 0; r < 4; ++r)
        outp[(size_t)(e0 + r) * Dh + d] = f2b(acc[i][j][r]);
    }
  }
}

// ---------------------------------------------------------------------------
// Exclusive cumsum over chunks, in place (f32 running sum). One kernel:
// first 2048 blocks handle KVT elements, last 16 blocks handle KS.
// ---------------------------------------------------------------------------
__global__ __launch_bounds__(256) void cumsum_all(u16* __restrict__ KVT,
                                                  float* __restrict__ KS)
{
  const int nkv = (Bsz * Hn * Dh * Dh) / 256;    // 2048
  if ((int)blockIdx.x < nkv) {
    const int tid = blockIdx.x * 256 + threadIdx.x;
    const int ed = tid & (Dh * Dh - 1);
    const int bh = tid >> 14;
    const int h = bh % Hn, b = bh / Hn;
    const size_t base = ((size_t)(b * NCh * Hn) + h) * (Dh * Dh) + ed;
    const size_t stride = (size_t)Hn * Dh * Dh;
    float s = 0.0f;
    for (int n = 0; n < NCh; ++n) {
      const size_t idx = base + (size_t)n * stride;
      const float v = b2f(KVT[idx]);
      KVT[idx] = f2b(s);
      s += v;
    }
  } else {
    const int tid = (blockIdx.x - nkv) * 256 + threadIdx.x;  // B*H*D threads
    const int d = tid & (Dh - 1);
    const int bh = tid >> 7;
    const int h = bh % Hn, b = bh / Hn;
    const size_t base = ((size_t)(b * NCh * Hn) + h) * Dh + d;
    const size_t stride = (size_t)Hn * Dh;
    float s = 0.0f;
    for (int n = 0; n < NCh; ++n) {
      const size_t idx = base + (size_t)n * stride;
      const float v = KS[idx];
      KS[idx] = s;
      s += v;
    }
  }
}

// ---------------------------------------------------------------------------
// Pass 2, per (b,n,h): A = tril(qf.kf^T); y = (A.v + qf.kv_ex) / (z+eps)
// Y may alias QF (block stages its QF rows into LDS before writing Y).
// ---------------------------------------------------------------------------
__global__ __launch_bounds__(256) void pass2_attn(
    const u16* __restrict__ QF, const u16* __restrict__ KF, const u16* __restrict__ V,
    const u16* __restrict__ KVT, const float* __restrict__ KSE,
    u16* __restrict__ Y)
{
  constexpr int LD = 136;
  __shared__ u16 smem[4 * 128 * LD];
  __shared__ float zpart[2][128];
  u16* sQ  = smem;
  u16* sK  = smem + 128 * LD;      // kf, later reused for v
  u16* sA  = smem + 2 * 128 * LD;
  u16* sKV = smem + 3 * 128 * LD;

  const int bnh = blockIdx.x;
  const int h = bnh % Hn, n = (bnh / Hn) % NCh, b = bnh / (Hn * NCh);
  const size_t rowbase = (size_t)(b * Ssz + n * Cch) * HID + h * Dh;
  const int t = threadIdx.x, lane = t & 63, w = t >> 6;
  const int wr = (w >> 1) * 64, wc = (w & 1) * 64;
  const int l15 = lane & 15, lg = lane >> 4;
  const int sr = t >> 4, sc = (t & 15) * 8;

  const u16* __restrict__ kvsrc = KVT + (size_t)bnh * (Dh * Dh);
#pragma unroll
  for (int rep = 0; rep < 8; ++rep) {
    const int r = rep * 16 + sr;
    *(int4v*)&sQ[r * LD + sc]  = *(const int4v*)&QF[rowbase + (size_t)r * HID + sc];
    *(int4v*)&sK[r * LD + sc]  = *(const int4v*)&KF[rowbase + (size_t)r * HID + sc];
    *(int4v*)&sKV[r * LD + sc] = *(const int4v*)&kvsrc[r * Dh + sc];
  }
  __syncthreads();

  // --- QK^T ---
  f32x4 acc[4][4] = {};
#pragma unroll
  for (int kk = 0; kk < 4; ++kk) {
    const int krd = kk * 32 + lg * 8;
    short8 aF[4], bF[4];
#pragma unroll
    for (int i = 0; i < 4; ++i)
      aF[i] = *(const short8*)&sQ[(wr + i * 16 + l15) * LD + krd];
#pragma unroll
    for (int j = 0; j < 4; ++j)
      bF[j] = *(const short8*)&sK[(wc + j * 16 + l15) * LD + krd];
#pragma unroll
    for (int i = 0; i < 4; ++i)
#pragma unroll
      for (int j = 0; j < 4; ++j)
        acc[i][j] = MFMA16(aF[i], bF[j], acc[i][j], 0, 0, 0);
  }
  // causal mask + write A to LDS (bf16)
#pragma unroll
  for (int i = 0; i < 4; ++i) {
    const int c0 = wr + i * 16 + lg * 4;
#pragma unroll
    for (int j = 0; j < 4; ++j) {
      const int ck = wc + j * 16 + l15;
#pragma unroll
      for (int r = 0; r < 4; ++r) {
        const int c = c0 + r;
        sA[c * LD + ck] = f2b((ck <= c) ? acc[i][j][r] : 0.0f);
      }
    }
  }
  __syncthreads();

  // --- z per row: t<128 does kse-dot for row t, t>=128 sums A row t-128;
  //     all threads stage V over kf ---
  if (t < 128) {
    const float* kse = KSE + (size_t)bnh * Dh;
    float zz = 0.0f;
    for (int d2 = 0; d2 < 128; ++d2) zz += b2f(sQ[t * LD + d2]) * kse[d2];
    zpart[0][t] = zz;
  } else {
    const int row = t - 128;
    float zz = 0.0f;
    for (int ck = 0; ck < 128; ++ck) zz += b2f(sA[row * LD + ck]);
    zpart[1][row] = zz;
  }
#pragma unroll
  for (int rep = 0; rep < 8; ++rep) {
    const int r = rep * 16 + sr;
    *(int4v*)&sK[r * LD + sc] = *(const int4v*)&V[rowbase + (size_t)r * HID + sc];
  }
  __syncthreads();

  // --- intra: o += A . v ---
  f32x4 o[4][4] = {};
#pragma unroll
  for (int kk = 0; kk < 4; ++kk) {
    const int krd = kk * 32 + lg * 8;
    short8 aF[4], bF[4];
#pragma unroll
    for (int i = 0; i < 4; ++i)
      aF[i] = *(const short8*)&sA[(wr + i * 16 + l15) * LD + krd];
#pragma unroll
    for (int j = 0; j < 4; ++j) {
      const int e = wc + j * 16 + l15;
      short8 bb;
#pragma unroll
      for (int u = 0; u < 8; ++u) bb[u] = (short)sK[(krd + u) * LD + e];
      bF[j] = bb;
    }
#pragma unroll
    for (int i = 0; i < 4; ++i)
#pragma unroll
      for (int j = 0; j < 4; ++j)
        o[i][j] = MFMA16(aF[i], bF[j], o[i][j], 0, 0, 0);
  }
  // --- inter: o += qf . kv_ex ---
#pragma unroll
  for (int kk = 0; kk < 4; ++kk) {
    const int krd = kk * 32 + lg * 8;
    short8 aF[4], bF[4];
#pragma unroll
    for (int i = 0; i < 4; ++i)
      aF[i] = *(const short8*)&sQ[(wr + i * 16 + l15) * LD + krd];
#pragma unroll
    for (int j = 0; j < 4; ++j)
      bF[j] = *(const short8*)&sKV[(wc + j * 16 + l15) * LD + krd];
#pragma unroll
    for (int i = 0; i < 4; ++i)
#pragma unroll
      for (int j = 0; j < 4; ++j)
        o[i][j] = MFMA16(aF[i], bF[j], o[i][j], 0, 0, 0);
  }

  // --- normalize + store y ---
#pragma unroll
  for (int i = 0; i < 4; ++i) {
    const int c0 = wr + i * 16 + lg * 4;
#pragma unroll
    for (int j = 0; j < 4; ++j) {
      const int e = wc + j * 16 + l15;
#pragma unroll
      for (int r = 0; r < 4; ++r) {
        const int c = c0 + r;
        const float zz = zpart[0][c] + zpart[1][c] + EPSf;
        Y[rowbase + (size_t)c * HID + e] = f2b(o[i][j][r] / zz);
      }
    }
  }
}

// ---------------------------------------------------------------------------
extern "C" void kernel_launch(void* const* d_in, const int* in_sizes, int n_in,
                              void* d_out, int out_size, void* d_ws, size_t ws_size,
                              hipStream_t stream)
{
  const float* x  = (const float*)d_in[0];
  const float* Wq = (const float*)d_in[1];
  const float* bq = (const float*)d_in[2];
  const float* Wk = (const float*)d_in[3];
  const float* bk = (const float*)d_in[4];
  const float* Wv = (const float*)d_in[5];
  const float* bv = (const float*)d_in[6];
  const float* Wo = (const float*)d_in[7];
  const float* bo = (const float*)d_in[8];
  float* out = (float*)d_out;

  char* p = (char*)d_ws;
  auto take = [&](size_t bytes) { char* q = p; p += (bytes + 255) & ~(size_t)255; return q; };
  u16* WqT = (u16*)take((size_t)HID * HID * 2);
  u16* WkT = (u16*)take((size_t)HID * HID * 2);
  u16* WvT = (u16*)take((size_t)HID * HID * 2);
  u16* WoT = (u16*)take((size_t)HID * HID * 2);
  u16* QF  = (u16*)take((size_t)Bsz * Ssz * HID * 2);   // later aliased as Y
  u16* KFb = (u16*)take((size_t)Bsz * Ssz * HID * 2);
  u16* Vb  = (u16*)take((size_t)Bsz * Ssz * HID * 2);
  // xb (bf16 x) aliases KVT: xb is dead once the QKV GEMM finishes.
  char* region = take((size_t)Bsz * Ssz * HID * 2);
  u16* xb  = (u16*)region;
  u16* KVT = (u16*)region;                               // 33.5 MB shared
  float* KS = (float*)take((size_t)Bsz * NCh * Hn * Dh * 4);
  u16* Yb = QF;   // safe alias: pass2 stages QF rows into LDS before writing Y

  // 64 KiB dynamic LDS for the GEMM (host-side attr set; capture-safe)
  (void)hipFuncSetAttribute((const void*)gemm2blk<0>,
                            hipFuncAttributeMaxDynamicSharedMemorySize, 65536);
  (void)hipFuncSetAttribute((const void*)gemm2blk<1>,
                            hipFuncAttributeMaxDynamicSharedMemorySize, 65536);

  dim3 blk(256, 1, 1);
  cvt_bf16<<<dim3(2048), blk, 0, stream>>>(x, xb);
  transpose4<<<dim3(HID / 64, HID / 64, 4), blk, 0, stream>>>(
      Wq, Wk, Wv, Wo, WqT, WkT, WvT, WoT);
  gemm2blk<0><<<dim3(HID / 256, (Bsz * Ssz) / 256, 3), dim3(512), 65536, stream>>>(
      xb, WqT, WkT, WvT, bq, bk, bv, QF, KFb, Vb, 0x3);
  pass1_kv<<<dim3(Bsz * NCh * Hn), blk, 0, stream>>>(KFb, Vb, KVT, KS);
  cumsum_all<<<dim3((Bsz * Hn * Dh * Dh) / 256 + (Bsz * Hn * Dh) / 256), blk, 0, stream>>>(KVT, KS);
  pass2_attn<<<dim3(Bsz * NCh * Hn), blk, 0, stream>>>(QF, KFb, Vb, KVT, KS, Yb);
  gemm2blk<1><<<dim3(HID / 256, (Bsz * Ssz) / 256, 1), dim3(512), 65536, stream>>>(
      Yb, WoT, WoT, WoT, bo, bo, bo, out, out, out, 0);
}

// Round 11
// 400.197 us; speedup vs baseline: 1.0134x; 1.0134x over previous
//
#include <hip/hip_runtime.h>

typedef unsigned short u16;
typedef unsigned int u32;
typedef unsigned long long u64;
typedef __attribute__((ext_vector_type(8))) short short8;
typedef __attribute__((ext_vector_type(4))) float f32x4;
typedef __attribute__((ext_vector_type(4))) int int4v;

constexpr int Bsz = 2, Ssz = 4096, Hn = 16, Dh = 128, HID = 2048;
constexpr int Cch = 128, NCh = 32;
constexpr float EPSf = 1e-6f;

#define MFMA16 __builtin_amdgcn_mfma_f32_16x16x32_bf16
#define VMW(N) asm volatile("s_waitcnt vmcnt(" #N ")" ::: "memory")
#define LGKM0  asm volatile("s_waitcnt lgkmcnt(0)" ::: "memory")

__device__ __forceinline__ float b2f(u16 u) {
  unsigned int i = ((unsigned int)u) << 16;
  return __builtin_bit_cast(float, i);
}
__device__ __forceinline__ u16 f2b(float f) {
  unsigned int i = __builtin_bit_cast(unsigned int, f);
  i += 0x7fffu + ((i >> 16) & 1u);   // round-to-nearest-even
  return (u16)(i >> 16);
}

// async global->LDS, 16 B per lane; LDS dest = wave-uniform base + lane*16.
__device__ __forceinline__ void gload_lds16(const u16* g, u16* l) {
  __builtin_amdgcn_global_load_lds(
      (const __attribute__((address_space(1))) u32*)g,
      (__attribute__((address_space(3))) u32*)l, 16, 0, 0);
}

// ---------------------------------------------------------------------------
// x f32 -> bf16 (streaming, vectorized)
// ---------------------------------------------------------------------------
__global__ __launch_bounds__(256) void cvt_bf16(const float* __restrict__ x,
                                                u16* __restrict__ xb)
{
  const size_t n8 = (size_t)Bsz * Ssz * HID / 8;
  for (size_t i = (size_t)blockIdx.x * 256 + threadIdx.x; i < n8;
       i += (size_t)gridDim.x * 256) {
    const f32x4 a = *(const f32x4*)&x[i * 8];
    const f32x4 b = *(const f32x4*)&x[i * 8 + 4];
    u16 tmp[8];
#pragma unroll
    for (int u = 0; u < 4; ++u) { tmp[u] = f2b(a[u]); tmp[u + 4] = f2b(b[u]); }
    *(int4v*)&xb[i * 8] = *(const int4v*)tmp;
  }
}

// ---------------------------------------------------------------------------
// Weight transpose+convert: W f32 [K][N] -> WT bf16 [N][K], 64x64 tiles.
// ---------------------------------------------------------------------------
__global__ __launch_bounds__(256) void transpose4(
    const float* __restrict__ A0, const float* __restrict__ A1,
    const float* __restrict__ A2, const float* __restrict__ A3,
    u16* __restrict__ T0, u16* __restrict__ T1,
    u16* __restrict__ T2, u16* __restrict__ T3)
{
  constexpr int N = HID, LDT = 72;
  const int z = blockIdx.z;
  const float* __restrict__ A = (z == 0) ? A0 : (z == 1) ? A1 : (z == 2) ? A2 : A3;
  u16* __restrict__ T = (z == 0) ? T0 : (z == 1) ? T1 : (z == 2) ? T2 : T3;
  __shared__ u16 lds[64 * LDT];
  const int t = threadIdx.x;
  const int i = t >> 3, j = (t & 7) * 8;
  const int r0 = blockIdx.y * 64, c0 = blockIdx.x * 64;
#pragma unroll
  for (int half = 0; half < 2; ++half) {
    const int r = i + half * 32;
    const f32x4 a = *(const f32x4*)&A[(size_t)(r0 + r) * N + c0 + j];
    const f32x4 b = *(const f32x4*)&A[(size_t)(r0 + r) * N + c0 + j + 4];
    u16 tmp[8];
#pragma unroll
    for (int u = 0; u < 4; ++u) { tmp[u] = f2b(a[u]); tmp[u + 4] = f2b(b[u]); }
    *(int4v*)&lds[r * LDT + j] = *(const int4v*)tmp;
  }
  __syncthreads();
#pragma unroll
  for (int half = 0; half < 2; ++half) {
    const int c = i + half * 32;
    u16 tmp[8];
#pragma unroll
    for (int u = 0; u < 8; ++u) tmp[u] = lds[(j + u) * LDT + c];
    *(int4v*)&T[(size_t)(c0 + c) * N + r0 + j] = *(const int4v*)tmp;
  }
}

// ---------------------------------------------------------------------------
// Fine-phase + deep-prefetch 256x256 GEMM (m201 pattern on r9 base):
// BK=32, 4-buffer rotation (depth-3), 8 waves (2Mx4N), LDS 128 KiB
// [buf4][A|B][256][32] slot-swizzled. Per tile: 2 phases, each
// {ds_read subtile, stage 2 gloads, (vmcnt), bar, lgkmcnt(0), 16 MFMA, bar}.
// vmcnt(8) once per tile waits on loads issued 2 windows ago (free).
// ---------------------------------------------------------------------------
template <int OUTF32>
__global__ __launch_bounds__(512) void gemm_fp(
    const u16* __restrict__ A,
    const u16* __restrict__ W0T, const u16* __restrict__ W1T, const u16* __restrict__ W2T,
    const float* __restrict__ bb0, const float* __restrict__ bb1, const float* __restrict__ bb2,
    void* __restrict__ o0, void* __restrict__ o1, void* __restrict__ o2,
    int elu_mask)
{
  constexpr int K = HID, N = HID;
  extern __shared__ u16 lds[];             // 65536 elems = 128 KiB

  const int z = blockIdx.z;
  const u16* __restrict__ WT    = (z == 0) ? W0T : (z == 1) ? W1T : W2T;
  const float* __restrict__ bias = (z == 0) ? bb0 : (z == 1) ? bb1 : bb2;
  void* __restrict__ outv = (z == 0) ? o0 : (z == 1) ? o1 : o2;
  const bool elu = (elu_mask >> z) & 1;

  // 2-D XCD map: XCD k owns m-band of 4 m-tiles x all 8 n-tiles.
  const int lid = blockIdx.x + 8 * blockIdx.y;   // 256 blocks/slice
  const int k8 = lid & 7, j32 = lid >> 3;
  const int m0 = (k8 * 4 + (j32 >> 3)) * 256;
  const int n0 = (j32 & 7) * 256;

  const int t = threadIdx.x, lane = t & 63, w = t >> 6;  // 8 waves
  const int wm = w >> 2, wn = w & 3;
  const int l15 = lane & 15, lg = lane >> 4;
  const int sl2 = (l15 >> 1) & 3;          // read-side swizzle key

  // staging: stored slot s holds global slot s ^ ((row>>1)&3).
  const int strow = lane >> 2;                              // 0..15
  const int stslot = (lane & 3) ^ ((lane >> 3) & 3);        // swizzled src slot
  const u16* gA = A  + (size_t)(m0 + w * 16 + strow) * K + stslot * 8;
  const u16* gB = WT + (size_t)(n0 + w * 16 + strow) * K + stslot * 8;

  // per-thread LDS read offsets (elems); buf b base = b*16384 (A), +8192 (B)
  const int aRow = (wm * 128 + l15) * 32 + ((lg ^ sl2) << 3);
  const int bRow = 8192 + (wn * 64 + l15) * 32 + ((lg ^ sl2) << 3);
  u16* const lw = &lds[w * 512];           // wave's staging base

  f32x4 acc[8][4] = {};
  short8 aF[8], bF[4];

  // Phase 1 of tile in BUF: read aF x8 + bF0,1; stage A-pair of tile+3 -> SB
#define PH1(BUF, SB, PF) do {                                                 \
    _Pragma("unroll")                                                         \
    for (int i = 0; i < 8; ++i)                                               \
      aF[i] = *(const short8*)&lds[(BUF)*16384 + aRow + i*512];               \
    bF[0] = *(const short8*)&lds[(BUF)*16384 + bRow];                         \
    bF[1] = *(const short8*)&lds[(BUF)*16384 + bRow + 512];                   \
    if (PF) {                                                                 \
      gload_lds16(gA,                 lw + (SB)*16384);                       \
      gload_lds16(gA + (size_t)128*K, lw + (SB)*16384 + 4096);                \
      gA += 32;                                                               \
    }                                                                         \
    __builtin_amdgcn_s_barrier();                                             \
    LGKM0;                                                                    \
    __builtin_amdgcn_s_setprio(1);                                            \
    _Pragma("unroll")                                                         \
    for (int i = 0; i < 8; ++i) {                                             \
      acc[i][0] = MFMA16(aF[i], bF[0], acc[i][0], 0, 0, 0);                   \
      acc[i][1] = MFMA16(aF[i], bF[1], acc[i][1], 0, 0, 0);                   \
    }                                                                         \
    __builtin_amdgcn_s_setprio(0);                                            \
    __builtin_amdgcn_s_barrier();                                             \
  } while (0)

  // Phase 2: read bF2,3; stage B-pair of tile+3 -> SB; counted vmcnt; MFMA
#define PH2(BUF, SB, PF, VMN) do {                                            \
    bF[2] = *(const short8*)&lds[(BUF)*16384 + bRow + 1024];                  \
    bF[3] = *(const short8*)&lds[(BUF)*16384 + bRow + 1536];                  \
    if (PF) {                                                                 \
      gload_lds16(gB,                 lw + (SB)*16384 + 8192);                 \
      gload_lds16(gB + (size_t)128*K, lw + (SB)*16384 + 8192 + 4096);          \
      gB += 32;                                                               \
    }                                                                         \
    VMW(VMN);                                                                 \
    __builtin_amdgcn_s_barrier();                                             \
    LGKM0;                                                                    \
    __builtin_amdgcn_s_setprio(1);                                            \
    _Pragma("unroll")                                                         \
    for (int i = 0; i < 8; ++i) {                                             \
      acc[i][2] = MFMA16(aF[i], bF[2], acc[i][2], 0, 0, 0);                   \
      acc[i][3] = MFMA16(aF[i], bF[3], acc[i][3], 0, 0, 0);                   \
    }                                                                         \
    __builtin_amdgcn_s_setprio(0);                                            \
    __builtin_amdgcn_s_barrier();                                             \
  } while (0)

  // prologue: stage tiles 0,1,2 into bufs 0,1,2 (A-pair then B-pair per tile)
#pragma unroll
  for (int pt = 0; pt < 3; ++pt) {
    gload_lds16(gA,                 lw + pt*16384);
    gload_lds16(gA + (size_t)128*K, lw + pt*16384 + 4096);
    gload_lds16(gB,                 lw + pt*16384 + 8192);
    gload_lds16(gB + (size_t)128*K, lw + pt*16384 + 8192 + 4096);
    gA += 32; gB += 32;
  }
  VMW(8);                              // tile 0 landed (oldest 4 of 12)
  __builtin_amdgcn_s_barrier();

  // 64 tiles; main loop covers t=0..59 (all stage t+3<=62, vmcnt(8))
  for (int W = 0; W < 60; W += 4) {
    PH1(0, 3, 1); PH2(0, 3, 1, 8);
    PH1(1, 0, 1); PH2(1, 0, 1, 8);
    PH1(2, 1, 1); PH2(2, 1, 1, 8);
    PH1(3, 2, 1); PH2(3, 2, 1, 8);
  }
  // tail: t=60 (stages tile 63), 61, 62, 63
  PH1(0, 3, 1); PH2(0, 3, 1, 8);
  PH1(1, 0, 0); PH2(1, 0, 0, 4);
  PH1(2, 0, 0); PH2(2, 0, 0, 0);
  PH1(3, 0, 0); PH2(3, 0, 0, 0);

  // epilogue
#pragma unroll
  for (int j = 0; j < 4; ++j) {
    const int col = n0 + wn * 64 + j * 16 + l15;
    const float bv = bias[col];
#pragma unroll
    for (int i = 0; i < 8; ++i) {
      const int row0 = m0 + wm * 128 + i * 16 + lg * 4;
#pragma unroll
      for (int r = 0; r < 4; ++r) {
        float v = acc[i][j][r] + bv;
        if (elu) v = (v > 0.0f) ? (v + 1.0f) : __expf(v);   // elu(x)+1
        if (OUTF32) ((float*)outv)[(size_t)(row0 + r) * N + col] = v;
        else        ((u16*)outv)[(size_t)(row0 + r) * N + col] = f2b(v);
      }
    }
  }
#undef PH1
#undef PH2
}

// ---------------------------------------------------------------------------
// Pass 1, per (b,n,h): kvT[e][d] = sum_c v[c,e]*kf[c,d];  ksum[d] = sum_c kf[c,d]
// ---------------------------------------------------------------------------
__global__ __launch_bounds__(256) void pass1_kv(
    const u16* __restrict__ KF, const u16* __restrict__ V,
    u16* __restrict__ KVT, float* __restrict__ KSUM)
{
  constexpr int LD = 136;
  __shared__ u16 lk[128 * LD];
  __shared__ u16 lv[128 * LD];
  __shared__ float kp[256];
  const int bnh = blockIdx.x;
  const int h = bnh % Hn, n = (bnh / Hn) % NCh, b = bnh / (Hn * NCh);
  const size_t rowbase = (size_t)(b * Ssz + n * Cch) * HID + h * Dh;
  const int t = threadIdx.x, lane = t & 63, w = t >> 6;
  const int wr = (w >> 1) * 64, wc = (w & 1) * 64;
  const int l15 = lane & 15, lg = lane >> 4;
  const int sr = t >> 4, sc = (t & 15) * 8;

#pragma unroll
  for (int rep = 0; rep < 8; ++rep) {
    const int r = rep * 16 + sr;
    *(int4v*)&lk[r * LD + sc] = *(const int4v*)&KF[rowbase + (size_t)r * HID + sc];
    *(int4v*)&lv[r * LD + sc] = *(const int4v*)&V[rowbase + (size_t)r * HID + sc];
  }
  __syncthreads();

  // ksum: 256 threads, each sums 64 rows for col (t&127)
  {
    const int col = t & 127, hf = t >> 7;
    float s = 0.0f;
    for (int c = hf * 64; c < hf * 64 + 64; ++c) s += b2f(lk[c * LD + col]);
    kp[t] = s;
  }
  __syncthreads();
  if (t < 128) KSUM[(size_t)bnh * Dh + t] = kp[t] + kp[t + 128];

  f32x4 acc[4][4] = {};
#pragma unroll
  for (int kk = 0; kk < 4; ++kk) {
    const int cb = kk * 32 + lg * 8;
    short8 aF[4], bF[4];
#pragma unroll
    for (int i = 0; i < 4; ++i) {           // A[e][c] = v[c][e]
      const int e = wr + i * 16 + l15;
      short8 a;
#pragma unroll
      for (int u = 0; u < 8; ++u) a[u] = (short)lv[(cb + u) * LD + e];
      aF[i] = a;
    }
#pragma unroll
    for (int j = 0; j < 4; ++j) {           // B[c][d] = kf[c][d]
      const int d = wc + j * 16 + l15;
      short8 bb;
#pragma unroll
      for (int u = 0; u < 8; ++u) bb[u] = (short)lk[(cb + u) * LD + d];
      bF[j] = bb;
    }
#pragma unroll
    for (int i = 0; i < 4; ++i)
#pragma unroll
      for (int j = 0; j < 4; ++j)
        acc[i][j] = MFMA16(aF[i], bF[j], acc[i][j], 0, 0, 0);
  }

  u16* __restrict__ outp = KVT + (size_t)bnh * (Dh * Dh);
#pragma unroll
  for (int i = 0; i < 4; ++i) {
    const int e0 = wr + i * 16 + lg * 4;
#pragma unroll
    for (int j = 0; j < 4; ++j) {
      const int d = wc + j * 16 + l15;
#pragma unroll
      for (int r = 0; r < 4; ++r)
        outp[(size_t)(e0 + r) * Dh + d] = f2b(acc[i][j][r]);
    }
  }
}

// ---------------------------------------------------------------------------
// Exclusive cumsum over chunks, in place (f32 running sum). One kernel:
// first 2048 blocks handle KVT elements, last 16 blocks handle KS.
// ---------------------------------------------------------------------------
__global__ __launch_bounds__(256) void cumsum_all(u16* __restrict__ KVT,
                                                  float* __restrict__ KS)
{
  const int nkv = (Bsz * Hn * Dh * Dh) / 256;    // 2048
  if ((int)blockIdx.x < nkv) {
    const int tid = blockIdx.x * 256 + threadIdx.x;
    const int ed = tid & (Dh * Dh - 1);
    const int bh = tid >> 14;
    const int h = bh % Hn, b = bh / Hn;
    const size_t base = ((size_t)(b * NCh * Hn) + h) * (Dh * Dh) + ed;
    const size_t stride = (size_t)Hn * Dh * Dh;
    float s = 0.0f;
    for (int n = 0; n < NCh; ++n) {
      const size_t idx = base + (size_t)n * stride;
      const float v = b2f(KVT[idx]);
      KVT[idx] = f2b(s);
      s += v;
    }
  } else {
    const int tid = (blockIdx.x - nkv) * 256 + threadIdx.x;  // B*H*D threads
    const int d = tid & (Dh - 1);
    const int bh = tid >> 7;
    const int h = bh % Hn, b = bh / Hn;
    const size_t base = ((size_t)(b * NCh * Hn) + h) * Dh + d;
    const size_t stride = (size_t)Hn * Dh;
    float s = 0.0f;
    for (int n = 0; n < NCh; ++n) {
      const size_t idx = base + (size_t)n * stride;
      const float v = KS[idx];
      KS[idx] = s;
      s += v;
    }
  }
}

// ---------------------------------------------------------------------------
// Pass 2, per (b,n,h): A = tril(qf.kf^T); y = (A.v + qf.kv_ex) / (z+eps)
// Y may alias QF (block stages its QF rows into LDS before writing Y).
// ---------------------------------------------------------------------------
__global__ __launch_bounds__(256) void pass2_attn(
    const u16* __restrict__ QF, const u16* __restrict__ KF, const u16* __restrict__ V,
    const u16* __restrict__ KVT, const float* __restrict__ KSE,
    u16* __restrict__ Y)
{
  constexpr int LD = 136;
  __shared__ u16 smem[4 * 128 * LD];
  __shared__ float zpart[2][128];
  u16* sQ  = smem;
  u16* sK  = smem + 128 * LD;      // kf, later reused for v
  u16* sA  = smem + 2 * 128 * LD;
  u16* sKV = smem + 3 * 128 * LD;

  const int bnh = blockIdx.x;
  const int h = bnh % Hn, n = (bnh / Hn) % NCh, b = bnh / (Hn * NCh);
  const size_t rowbase = (size_t)(b * Ssz + n * Cch) * HID + h * Dh;
  const int t = threadIdx.x, lane = t & 63, w = t >> 6;
  const int wr = (w >> 1) * 64, wc = (w & 1) * 64;
  const int l15 = lane & 15, lg = lane >> 4;
  const int sr = t >> 4, sc = (t & 15) * 8;

  const u16* __restrict__ kvsrc = KVT + (size_t)bnh * (Dh * Dh);
#pragma unroll
  for (int rep = 0; rep < 8; ++rep) {
    const int r = rep * 16 + sr;
    *(int4v*)&sQ[r * LD + sc]  = *(const int4v*)&QF[rowbase + (size_t)r * HID + sc];
    *(int4v*)&sK[r * LD + sc]  = *(const int4v*)&KF[rowbase + (size_t)r * HID + sc];
    *(int4v*)&sKV[r * LD + sc] = *(const int4v*)&kvsrc[r * Dh + sc];
  }
  __syncthreads();

  // --- QK^T ---
  f32x4 acc[4][4] = {};
#pragma unroll
  for (int kk = 0; kk < 4; ++kk) {
    const int krd = kk * 32 + lg * 8;
    short8 aF[4], bF[4];
#pragma unroll
    for (int i = 0; i < 4; ++i)
      aF[i] = *(const short8*)&sQ[(wr + i * 16 + l15) * LD + krd];
#pragma unroll
    for (int j = 0; j < 4; ++j)
      bF[j] = *(const short8*)&sK[(wc + j * 16 + l15) * LD + krd];
#pragma unroll
    for (int i = 0; i < 4; ++i)
#pragma unroll
      for (int j = 0; j < 4; ++j)
        acc[i][j] = MFMA16(aF[i], bF[j], acc[i][j], 0, 0, 0);
  }
  // causal mask + write A to LDS (bf16)
#pragma unroll
  for (int i = 0; i < 4; ++i) {
    const int c0 = wr + i * 16 + lg * 4;
#pragma unroll
    for (int j = 0; j < 4; ++j) {
      const int ck = wc + j * 16 + l15;
#pragma unroll
      for (int r = 0; r < 4; ++r) {
        const int c = c0 + r;
        sA[c * LD + ck] = f2b((ck <= c) ? acc[i][j][r] : 0.0f);
      }
    }
  }
  __syncthreads();

  // --- z per row: t<128 does kse-dot for row t, t>=128 sums A row t-128;
  //     all threads stage V over kf ---
  if (t < 128) {
    const float* kse = KSE + (size_t)bnh * Dh;
    float zz = 0.0f;
    for (int d2 = 0; d2 < 128; ++d2) zz += b2f(sQ[t * LD + d2]) * kse[d2];
    zpart[0][t] = zz;
  } else {
    const int row = t - 128;
    float zz = 0.0f;
    for (int ck = 0; ck < 128; ++ck) zz += b2f(sA[row * LD + ck]);
    zpart[1][row] = zz;
  }
#pragma unroll
  for (int rep = 0; rep < 8; ++rep) {
    const int r = rep * 16 + sr;
    *(int4v*)&sK[r * LD + sc] = *(const int4v*)&V[rowbase + (size_t)r * HID + sc];
  }
  __syncthreads();

  // --- intra: o += A . v ---
  f32x4 o[4][4] = {};
#pragma unroll
  for (int kk = 0; kk < 4; ++kk) {
    const int krd = kk * 32 + lg * 8;
    short8 aF[4], bF[4];
#pragma unroll
    for (int i = 0; i < 4; ++i)
      aF[i] = *(const short8*)&sA[(wr + i * 16 + l15) * LD + krd];
#pragma unroll
    for (int j = 0; j < 4; ++j) {
      const int e = wc + j * 16 + l15;
      short8 bb;
#pragma unroll
      for (int u = 0; u < 8; ++u) bb[u] = (short)sK[(krd + u) * LD + e];
      bF[j] = bb;
    }
#pragma unroll
    for (int i = 0; i < 4; ++i)
#pragma unroll
      for (int j = 0; j < 4; ++j)
        o[i][j] = MFMA16(aF[i], bF[j], o[i][j], 0, 0, 0);
  }
  // --- inter: o += qf . kv_ex ---
#pragma unroll
  for (int kk = 0; kk < 4; ++kk) {
    const int krd = kk * 32 + lg * 8;
    short8 aF[4], bF[4];
#pragma unroll
    for (int i = 0; i < 4; ++i)
      aF[i] = *(const short8*)&sQ[(wr + i * 16 + l15) * LD + krd];
#pragma unroll
    for (int j = 0; j < 4; ++j)
      bF[j] = *(const short8*)&sKV[(wc + j * 16 + l15) * LD + krd];
#pragma unroll
    for (int i = 0; i < 4; ++i)
#pragma unroll
      for (int j = 0; j < 4; ++j)
        o[i][j] = MFMA16(aF[i], bF[j], o[i][j], 0, 0, 0);
  }

  // --- normalize + store y ---
#pragma unroll
  for (int i = 0; i < 4; ++i) {
    const int c0 = wr + i * 16 + lg * 4;
#pragma unroll
    for (int j = 0; j < 4; ++j) {
      const int e = wc + j * 16 + l15;
#pragma unroll
      for (int r = 0; r < 4; ++r) {
        const int c = c0 + r;
        const float zz = zpart[0][c] + zpart[1][c] + EPSf;
        Y[rowbase + (size_t)c * HID + e] = f2b(o[i][j][r] / zz);
      }
    }
  }
}

// ---------------------------------------------------------------------------
extern "C" void kernel_launch(void* const* d_in, const int* in_sizes, int n_in,
                              void* d_out, int out_size, void* d_ws, size_t ws_size,
                              hipStream_t stream)
{
  const float* x  = (const float*)d_in[0];
  const float* Wq = (const float*)d_in[1];
  const float* bq = (const float*)d_in[2];
  const float* Wk = (const float*)d_in[3];
  const float* bk = (const float*)d_in[4];
  const float* Wv = (const float*)d_in[5];
  const float* bv = (const float*)d_in[6];
  const float* Wo = (const float*)d_in[7];
  const float* bo = (const float*)d_in[8];
  float* out = (float*)d_out;

  char* p = (char*)d_ws;
  auto take = [&](size_t bytes) { char* q = p; p += (bytes + 255) & ~(size_t)255; return q; };
  u16* WqT = (u16*)take((size_t)HID * HID * 2);
  u16* WkT = (u16*)take((size_t)HID * HID * 2);
  u16* WvT = (u16*)take((size_t)HID * HID * 2);
  u16* WoT = (u16*)take((size_t)HID * HID * 2);
  u16* QF  = (u16*)take((size_t)Bsz * Ssz * HID * 2);   // later aliased as Y
  u16* KFb = (u16*)take((size_t)Bsz * Ssz * HID * 2);
  u16* Vb  = (u16*)take((size_t)Bsz * Ssz * HID * 2);
  // xb (bf16 x) aliases KVT: xb is dead once the QKV GEMM finishes.
  char* region = take((size_t)Bsz * Ssz * HID * 2);
  u16* xb  = (u16*)region;
  u16* KVT = (u16*)region;                               // 33.5 MB shared
  float* KS = (float*)take((size_t)Bsz * NCh * Hn * Dh * 4);
  u16* Yb = QF;   // safe alias: pass2 stages QF rows into LDS before writing Y

  // 128 KiB dynamic LDS for the GEMM (host-side attr set; capture-safe)
  (void)hipFuncSetAttribute((const void*)gemm_fp<0>,
                            hipFuncAttributeMaxDynamicSharedMemorySize, 131072);
  (void)hipFuncSetAttribute((const void*)gemm_fp<1>,
                            hipFuncAttributeMaxDynamicSharedMemorySize, 131072);

  dim3 blk(256, 1, 1);
  cvt_bf16<<<dim3(2048), blk, 0, stream>>>(x, xb);
  transpose4<<<dim3(HID / 64, HID / 64, 4), blk, 0, stream>>>(
      Wq, Wk, Wv, Wo, WqT, WkT, WvT, WoT);
  gemm_fp<0><<<dim3(HID / 256, (Bsz * Ssz) / 256, 3), dim3(512), 131072, stream>>>(
      xb, WqT, WkT, WvT, bq, bk, bv, QF, KFb, Vb, 0x3);
  pass1_kv<<<dim3(Bsz * NCh * Hn), blk, 0, stream>>>(KFb, Vb, KVT, KS);
  cumsum_all<<<dim3((Bsz * Hn * Dh * Dh) / 256 + (Bsz * Hn * Dh) / 256), blk, 0, stream>>>(KVT, KS);
  pass2_attn<<<dim3(Bsz * NCh * Hn), blk, 0, stream>>>(QF, KFb, Vb, KVT, KS, Yb);
  gemm_fp<1><<<dim3(HID / 256, (Bsz * Ssz) / 256, 1), dim3(512), 131072, stream>>>(
      Yb, WoT, WoT, WoT, bo, bo, bo, out, out, out, 0);
}

// Round 12
// 387.344 us; speedup vs baseline: 1.0471x; 1.0332x over previous
//
#include <hip/hip_runtime.h>

typedef unsigned short u16;
typedef unsigned int u32;
typedef unsigned long long u64;
typedef __attribute__((ext_vector_type(8))) short short8;
typedef __attribute__((ext_vector_type(4))) float f32x4;
typedef __attribute__((ext_vector_type(4))) int int4v;

constexpr int Bsz = 2, Ssz = 4096, Hn = 16, Dh = 128, HID = 2048;
constexpr int Cch = 128, NCh = 32;
constexpr float EPSf = 1e-6f;

#define MFMA16 __builtin_amdgcn_mfma_f32_16x16x32_bf16
#define VMW(N) asm volatile("s_waitcnt vmcnt(" #N ")" ::: "memory")

__device__ __forceinline__ float b2f(u16 u) {
  unsigned int i = ((unsigned int)u) << 16;
  return __builtin_bit_cast(float, i);
}
__device__ __forceinline__ u16 f2b(float f) {
  unsigned int i = __builtin_bit_cast(unsigned int, f);
  i += 0x7fffu + ((i >> 16) & 1u);   // round-to-nearest-even
  return (u16)(i >> 16);
}

// async global->LDS, 16 B per lane; LDS dest = wave-uniform base + lane*16.
__device__ __forceinline__ void gload_lds16(const u16* g, u16* l) {
  __builtin_amdgcn_global_load_lds(
      (const __attribute__((address_space(1))) u32*)g,
      (__attribute__((address_space(3))) u32*)l, 16, 0, 0);
}

// ---------------------------------------------------------------------------
// x f32 -> bf16 (streaming, vectorized)
// ---------------------------------------------------------------------------
__global__ __launch_bounds__(256) void cvt_bf16(const float* __restrict__ x,
                                                u16* __restrict__ xb)
{
  const size_t n8 = (size_t)Bsz * Ssz * HID / 8;
  for (size_t i = (size_t)blockIdx.x * 256 + threadIdx.x; i < n8;
       i += (size_t)gridDim.x * 256) {
    const f32x4 a = *(const f32x4*)&x[i * 8];
    const f32x4 b = *(const f32x4*)&x[i * 8 + 4];
    u16 tmp[8];
#pragma unroll
    for (int u = 0; u < 4; ++u) { tmp[u] = f2b(a[u]); tmp[u + 4] = f2b(b[u]); }
    *(int4v*)&xb[i * 8] = *(const int4v*)tmp;
  }
}

// ---------------------------------------------------------------------------
// Weight transpose+convert: W f32 [K][N] -> WT bf16 [N][K], 64x64 tiles.
// ---------------------------------------------------------------------------
__global__ __launch_bounds__(256) void transpose4(
    const float* __restrict__ A0, const float* __restrict__ A1,
    const float* __restrict__ A2, const float* __restrict__ A3,
    u16* __restrict__ T0, u16* __restrict__ T1,
    u16* __restrict__ T2, u16* __restrict__ T3)
{
  constexpr int N = HID, LDT = 72;
  const int z = blockIdx.z;
  const float* __restrict__ A = (z == 0) ? A0 : (z == 1) ? A1 : (z == 2) ? A2 : A3;
  u16* __restrict__ T = (z == 0) ? T0 : (z == 1) ? T1 : (z == 2) ? T2 : T3;
  __shared__ u16 lds[64 * LDT];
  const int t = threadIdx.x;
  const int i = t >> 3, j = (t & 7) * 8;
  const int r0 = blockIdx.y * 64, c0 = blockIdx.x * 64;
#pragma unroll
  for (int half = 0; half < 2; ++half) {
    const int r = i + half * 32;
    const f32x4 a = *(const f32x4*)&A[(size_t)(r0 + r) * N + c0 + j];
    const f32x4 b = *(const f32x4*)&A[(size_t)(r0 + r) * N + c0 + j + 4];
    u16 tmp[8];
#pragma unroll
    for (int u = 0; u < 4; ++u) { tmp[u] = f2b(a[u]); tmp[u + 4] = f2b(b[u]); }
    *(int4v*)&lds[r * LDT + j] = *(const int4v*)tmp;
  }
  __syncthreads();
#pragma unroll
  for (int half = 0; half < 2; ++half) {
    const int c = i + half * 32;
    u16 tmp[8];
#pragma unroll
    for (int u = 0; u < 8; ++u) tmp[u] = lds[(j + u) * LDT + c];
    *(int4v*)&T[(size_t)(c0 + c) * N + r0 + j] = *(const int4v*)tmp;
  }
}

// ---------------------------------------------------------------------------
// Deep-prefetch 256x256 GEMM (r9 schedule, frozen): BK=32, 4-buffer rotation
// (depth-3), 8 waves (2Mx4N), LDS 128 KiB [buf4][A|B][256][32] slot-swizzled.
// Per window: vmcnt(8) (loads 3 windows old - free), s_barrier, stage tile
// W+3, 12 ds_read + 32 MFMA. NEW: bf16 epilogue staged through LDS so HBM
// writes are full 128-B spans (was 32-B partial sectors, 2.3x amplification).
// ---------------------------------------------------------------------------
template <int OUTF32>
__global__ __launch_bounds__(512) void gemm4b(
    const u16* __restrict__ A,
    const u16* __restrict__ W0T, const u16* __restrict__ W1T, const u16* __restrict__ W2T,
    const float* __restrict__ bb0, const float* __restrict__ bb1, const float* __restrict__ bb2,
    void* __restrict__ o0, void* __restrict__ o1, void* __restrict__ o2,
    int elu_mask)
{
  constexpr int K = HID, N = HID;
  extern __shared__ u16 lds[];             // 65536 elems = 128 KiB

  const int z = blockIdx.z;
  const u16* __restrict__ WT    = (z == 0) ? W0T : (z == 1) ? W1T : W2T;
  const float* __restrict__ bias = (z == 0) ? bb0 : (z == 1) ? bb1 : bb2;
  void* __restrict__ outv = (z == 0) ? o0 : (z == 1) ? o1 : o2;
  const bool elu = (elu_mask >> z) & 1;

  // 2-D XCD map: XCD k owns m-band of 4 m-tiles x all 8 n-tiles.
  const int lid = blockIdx.x + 8 * blockIdx.y;   // 256 blocks/slice
  const int k8 = lid & 7, j32 = lid >> 3;        // XCD, index within XCD
  const int m0 = (k8 * 4 + (j32 >> 3)) * 256;
  const int n0 = (j32 & 7) * 256;

  const int t = threadIdx.x, lane = t & 63, w = t >> 6;  // 8 waves
  const int wm = w >> 2, wn = w & 3;
  const int l15 = lane & 15, lg = lane >> 4;
  const int sl2 = (l15 >> 1) & 3;          // read-side swizzle key

  // staging: stored slot s holds global slot s ^ ((row>>1)&3).
  const int strow = lane >> 2;                              // 0..15
  const int stslot = (lane & 3) ^ ((lane >> 3) & 3);        // swizzled src slot
  const u16* gA = A  + (size_t)(m0 + w * 16 + strow) * K + stslot * 8;
  const u16* gB = WT + (size_t)(n0 + w * 16 + strow) * K + stslot * 8;

  // per-thread LDS read offsets (elems); buf b base = b*16384 (A), +8192 (B)
  const int aRow = (wm * 128 + l15) * 32 + ((lg ^ sl2) << 3);
  const int bRow = 8192 + (wn * 64 + l15) * 32 + ((lg ^ sl2) << 3);
  u16* const lw = &lds[w * 512];           // wave's staging base

  f32x4 acc[8][4] = {};
  short8 aF[8], bF[4];

  // stage one 32-k tile into buffer SB (4 gloads), advance gA/gB
#define STAGE4(SB) do {                                                       \
    gload_lds16(gA,                   lw + (SB)*16384);                       \
    gload_lds16(gA + (size_t)128*K,   lw + (SB)*16384 + 4096);                \
    gload_lds16(gB,                   lw + (SB)*16384 + 8192);                \
    gload_lds16(gB + (size_t)128*K,   lw + (SB)*16384 + 8192 + 4096);         \
    gA += 32; gB += 32;                                                       \
  } while (0)

  // window: wait (free), barrier, stage depth-3 ahead, compute 32 MFMA
#define WINDOW(BUF, SB, PF, VMN) do {                                         \
    VMW(VMN);                                                                 \
    __builtin_amdgcn_s_barrier();                                             \
    if (PF) STAGE4(SB);                                                       \
    _Pragma("unroll")                                                         \
    for (int i = 0; i < 8; ++i)                                               \
      aF[i] = *(const short8*)&lds[(BUF)*16384 + aRow + i*512];               \
    _Pragma("unroll")                                                         \
    for (int j = 0; j < 4; ++j)                                               \
      bF[j] = *(const short8*)&lds[(BUF)*16384 + bRow + j*512];               \
    __builtin_amdgcn_s_setprio(1);                                            \
    _Pragma("unroll")                                                         \
    for (int i = 0; i < 8; ++i) {                                             \
      acc[i][0] = MFMA16(aF[i], bF[0], acc[i][0], 0, 0, 0);                   \
      acc[i][1] = MFMA16(aF[i], bF[1], acc[i][1], 0, 0, 0);                   \
      acc[i][2] = MFMA16(aF[i], bF[2], acc[i][2], 0, 0, 0);                   \
      acc[i][3] = MFMA16(aF[i], bF[3], acc[i][3], 0, 0, 0);                   \
    }                                                                         \
    __builtin_amdgcn_s_setprio(0);                                            \
  } while (0)

  // prologue: stage tiles 0,1,2 into bufs 0,1,2 (12 loads out)
  STAGE4(0);
  STAGE4(1);
  STAGE4(2);

  // 64 windows (K/32); W=0..59 in x4 unroll, each staging tile W+3
  for (int W = 0; W < 60; W += 4) {
    WINDOW(0, 3, 1, 8);
    WINDOW(1, 0, 1, 8);
    WINDOW(2, 1, 1, 8);
    WINDOW(3, 2, 1, 8);
  }
  WINDOW(0, 3, 1, 8);    // W=60: stages tile 63 into buf 3
  WINDOW(1, 0, 0, 8);    // W=61
  WINDOW(2, 0, 0, 4);    // W=62
  WINDOW(3, 0, 0, 0);    // W=63

  if (OUTF32) {
    // f32 direct stores: 16 lanes x 4 B = full 64-B sectors already
#pragma unroll
    for (int j = 0; j < 4; ++j) {
      const int col = n0 + wn * 64 + j * 16 + l15;
      const float bv = bias[col];
#pragma unroll
      for (int i = 0; i < 8; ++i) {
        const int row0 = m0 + wm * 128 + i * 16 + lg * 4;
#pragma unroll
        for (int r = 0; r < 4; ++r) {
          float v = acc[i][j][r] + bv;
          if (elu) v = (v > 0.0f) ? (v + 1.0f) : __expf(v);
          ((float*)outv)[(size_t)(row0 + r) * N + col] = v;
        }
      }
    }
  } else {
    // bf16: dump via LDS (buffers dead after this barrier), store 16-B vectors
    __builtin_amdgcn_s_barrier();          // all waves done reading buffers
    u16* const myr = &lds[w * 8192];       // this wave's 128x64 region
#pragma unroll
    for (int j = 0; j < 4; ++j) {
      const float bv = bias[n0 + wn * 64 + j * 16 + l15];
#pragma unroll
      for (int i = 0; i < 8; ++i)
#pragma unroll
        for (int r = 0; r < 4; ++r) {
          float v = acc[i][j][r] + bv;
          if (elu) v = (v > 0.0f) ? (v + 1.0f) : __expf(v);
          myr[(i * 16 + lg * 4 + r) * 64 + j * 16 + l15] = f2b(v);
        }
    }
    // readback own region only (no cross-wave): compiler orders ds ops
    const int rl = lane >> 3, ch = (lane & 7) * 8;
    u16* const og = (u16*)outv + (size_t)(m0 + wm * 128) * N + n0 + wn * 64;
#pragma unroll
    for (int si = 0; si < 16; ++si) {
      const int rw = si * 8 + rl;
      *(int4v*)&og[(size_t)rw * N + ch] = *(const int4v*)&myr[rw * 64 + ch];
    }
  }
#undef STAGE4
#undef WINDOW
}

// ---------------------------------------------------------------------------
// Pass 1, per (b,n,h): kvT[e][d] = sum_c v[c,e]*kf[c,d];  ksum[d] = sum_c kf[c,d]
// ---------------------------------------------------------------------------
__global__ __launch_bounds__(256) void pass1_kv(
    const u16* __restrict__ KF, const u16* __restrict__ V,
    u16* __restrict__ KVT, float* __restrict__ KSUM)
{
  constexpr int LD = 136;
  __shared__ u16 lk[128 * LD];
  __shared__ u16 lv[128 * LD];
  __shared__ float kp[256];
  const int bnh = blockIdx.x;
  const int h = bnh % Hn, n = (bnh / Hn) % NCh, b = bnh / (Hn * NCh);
  const size_t rowbase = (size_t)(b * Ssz + n * Cch) * HID + h * Dh;
  const int t = threadIdx.x, lane = t & 63, w = t >> 6;
  const int wr = (w >> 1) * 64, wc = (w & 1) * 64;
  const int l15 = lane & 15, lg = lane >> 4;
  const int sr = t >> 4, sc = (t & 15) * 8;

#pragma unroll
  for (int rep = 0; rep < 8; ++rep) {
    const int r = rep * 16 + sr;
    *(int4v*)&lk[r * LD + sc] = *(const int4v*)&KF[rowbase + (size_t)r * HID + sc];
    *(int4v*)&lv[r * LD + sc] = *(const int4v*)&V[rowbase + (size_t)r * HID + sc];
  }
  __syncthreads();

  // ksum: 256 threads, each sums 64 rows for col (t&127)
  {
    const int col = t & 127, hf = t >> 7;
    float s = 0.0f;
    for (int c = hf * 64; c < hf * 64 + 64; ++c) s += b2f(lk[c * LD + col]);
    kp[t] = s;
  }
  __syncthreads();
  if (t < 128) KSUM[(size_t)bnh * Dh + t] = kp[t] + kp[t + 128];

  f32x4 acc[4][4] = {};
#pragma unroll
  for (int kk = 0; kk < 4; ++kk) {
    const int cb = kk * 32 + lg * 8;
    short8 aF[4], bF[4];
#pragma unroll
    for (int i = 0; i < 4; ++i) {           // A[e][c] = v[c][e]
      const int e = wr + i * 16 + l15;
      short8 a;
#pragma unroll
      for (int u = 0; u < 8; ++u) a[u] = (short)lv[(cb + u) * LD + e];
      aF[i] = a;
    }
#pragma unroll
    for (int j = 0; j < 4; ++j) {           // B[c][d] = kf[c][d]
      const int d = wc + j * 16 + l15;
      short8 bb;
#pragma unroll
      for (int u = 0; u < 8; ++u) bb[u] = (short)lk[(cb + u) * LD + d];
      bF[j] = bb;
    }
#pragma unroll
    for (int i = 0; i < 4; ++i)
#pragma unroll
      for (int j = 0; j < 4; ++j)
        acc[i][j] = MFMA16(aF[i], bF[j], acc[i][j], 0, 0, 0);
  }

  u16* __restrict__ outp = KVT + (size_t)bnh * (Dh * Dh);
#pragma unroll
  for (int i = 0; i < 4; ++i) {
    const int e0 = wr + i * 16 + lg * 4;
#pragma unroll
    for (int j = 0; j < 4; ++j) {
      const int d = wc + j * 16 + l15;
#pragma unroll
      for (int r = 0; r < 4; ++r)
        outp[(size_t)(e0 + r) * Dh + d] = f2b(acc[i][j][r]);
    }
  }
}

// ---------------------------------------------------------------------------
// Exclusive cumsum over chunks, in place (f32 running sum). One kernel:
// first 2048 blocks handle KVT elements, last 16 blocks handle KS.
// ---------------------------------------------------------------------------
__global__ __launch_bounds__(256) void cumsum_all(u16* __restrict__ KVT,
                                                  float* __restrict__ KS)
{
  const int nkv = (Bsz * Hn * Dh * Dh) / 256;    // 2048
  if ((int)blockIdx.x < nkv) {
    const int tid = blockIdx.x * 256 + threadIdx.x;
    const int ed = tid & (Dh * Dh - 1);
    const int bh = tid >> 14;
    const int h = bh % Hn, b = bh / Hn;
    const size_t base = ((size_t)(b * NCh * Hn) + h) * (Dh * Dh) + ed;
    const size_t stride = (size_t)Hn * Dh * Dh;
    float s = 0.0f;
    for (int n = 0; n < NCh; ++n) {
      const size_t idx = base + (size_t)n * stride;
      const float v = b2f(KVT[idx]);
      KVT[idx] = f2b(s);
      s += v;
    }
  } else {
    const int tid = (blockIdx.x - nkv) * 256 + threadIdx.x;  // B*H*D threads
    const int d = tid & (Dh - 1);
    const int bh = tid >> 7;
    const int h = bh % Hn, b = bh / Hn;
    const size_t base = ((size_t)(b * NCh * Hn) + h) * Dh + d;
    const size_t stride = (size_t)Hn * Dh;
    float s = 0.0f;
    for (int n = 0; n < NCh; ++n) {
      const size_t idx = base + (size_t)n * stride;
      const float v = KS[idx];
      KS[idx] = s;
      s += v;
    }
  }
}

// ---------------------------------------------------------------------------
// Pass 2, per (b,n,h): A = tril(qf.kf^T); y = (A.v + qf.kv_ex) / (z+eps)
// Y may alias QF (block stages its QF rows into LDS before writing Y).
// ---------------------------------------------------------------------------
__global__ __launch_bounds__(256) void pass2_attn(
    const u16* __restrict__ QF, const u16* __restrict__ KF, const u16* __restrict__ V,
    const u16* __restrict__ KVT, const float* __restrict__ KSE,
    u16* __restrict__ Y)
{
  constexpr int LD = 136;
  __shared__ u16 smem[4 * 128 * LD];
  __shared__ float zpart[2][128];
  u16* sQ  = smem;
  u16* sK  = smem + 128 * LD;      // kf, later reused for v
  u16* sA  = smem + 2 * 128 * LD;
  u16* sKV = smem + 3 * 128 * LD;

  const int bnh = blockIdx.x;
  const int h = bnh % Hn, n = (bnh / Hn) % NCh, b = bnh / (Hn * NCh);
  const size_t rowbase = (size_t)(b * Ssz + n * Cch) * HID + h * Dh;
  const int t = threadIdx.x, lane = t & 63, w = t >> 6;
  const int wr = (w >> 1) * 64, wc = (w & 1) * 64;
  const int l15 = lane & 15, lg = lane >> 4;
  const int sr = t >> 4, sc = (t & 15) * 8;

  const u16* __restrict__ kvsrc = KVT + (size_t)bnh * (Dh * Dh);
#pragma unroll
  for (int rep = 0; rep < 8; ++rep) {
    const int r = rep * 16 + sr;
    *(int4v*)&sQ[r * LD + sc]  = *(const int4v*)&QF[rowbase + (size_t)r * HID + sc];
    *(int4v*)&sK[r * LD + sc]  = *(const int4v*)&KF[rowbase + (size_t)r * HID + sc];
    *(int4v*)&sKV[r * LD + sc] = *(const int4v*)&kvsrc[r * Dh + sc];
  }
  __syncthreads();

  // --- QK^T ---
  f32x4 acc[4][4] = {};
#pragma unroll
  for (int kk = 0; kk < 4; ++kk) {
    const int krd = kk * 32 + lg * 8;
    short8 aF[4], bF[4];
#pragma unroll
    for (int i = 0; i < 4; ++i)
      aF[i] = *(const short8*)&sQ[(wr + i * 16 + l15) * LD + krd];
#pragma unroll
    for (int j = 0; j < 4; ++j)
      bF[j] = *(const short8*)&sK[(wc + j * 16 + l15) * LD + krd];
#pragma unroll
    for (int i = 0; i < 4; ++i)
#pragma unroll
      for (int j = 0; j < 4; ++j)
        acc[i][j] = MFMA16(aF[i], bF[j], acc[i][j], 0, 0, 0);
  }
  // causal mask + write A to LDS (bf16)
#pragma unroll
  for (int i = 0; i < 4; ++i) {
    const int c0 = wr + i * 16 + lg * 4;
#pragma unroll
    for (int j = 0; j < 4; ++j) {
      const int ck = wc + j * 16 + l15;
#pragma unroll
      for (int r = 0; r < 4; ++r) {
        const int c = c0 + r;
        sA[c * LD + ck] = f2b((ck <= c) ? acc[i][j][r] : 0.0f);
      }
    }
  }
  __syncthreads();

  // --- z per row (vectorized): t<128 kse-dot row t; t>=128 sums A row t-128;
  //     all threads stage V over kf ---
  if (t < 128) {
    const float* kse = KSE + (size_t)bnh * Dh;
    float zz = 0.0f;
    for (int d2 = 0; d2 < 128; d2 += 8) {
      const short8 q8 = *(const short8*)&sQ[t * LD + d2];
      const f32x4 k0 = *(const f32x4*)&kse[d2];
      const f32x4 k1 = *(const f32x4*)&kse[d2 + 4];
      zz += b2f((u16)q8[0]) * k0[0] + b2f((u16)q8[1]) * k0[1]
          + b2f((u16)q8[2]) * k0[2] + b2f((u16)q8[3]) * k0[3]
          + b2f((u16)q8[4]) * k1[0] + b2f((u16)q8[5]) * k1[1]
          + b2f((u16)q8[6]) * k1[2] + b2f((u16)q8[7]) * k1[3];
    }
    zpart[0][t] = zz;
  } else {
    const int row = t - 128;
    float zz = 0.0f;
    for (int ck = 0; ck < 128; ck += 8) {
      const short8 a8 = *(const short8*)&sA[row * LD + ck];
#pragma unroll
      for (int u = 0; u < 8; ++u) zz += b2f((u16)a8[u]);
    }
    zpart[1][row] = zz;
  }
#pragma unroll
  for (int rep = 0; rep < 8; ++rep) {
    const int r = rep * 16 + sr;
    *(int4v*)&sK[r * LD + sc] = *(const int4v*)&V[rowbase + (size_t)r * HID + sc];
  }
  __syncthreads();

  // --- intra: o += A . v ---
  f32x4 o[4][4] = {};
#pragma unroll
  for (int kk = 0; kk < 4; ++kk) {
    const int krd = kk * 32 + lg * 8;
    short8 aF[4], bF[4];
#pragma unroll
    for (int i = 0; i < 4; ++i)
      aF[i] = *(const short8*)&sA[(wr + i * 16 + l15) * LD + krd];
#pragma unroll
    for (int j = 0; j < 4; ++j) {
      const int e = wc + j * 16 + l15;
      short8 bb;
#pragma unroll
      for (int u = 0; u < 8; ++u) bb[u] = (short)sK[(krd + u) * LD + e];
      bF[j] = bb;
    }
#pragma unroll
    for (int i = 0; i < 4; ++i)
#pragma unroll
      for (int j = 0; j < 4; ++j)
        o[i][j] = MFMA16(aF[i], bF[j], o[i][j], 0, 0, 0);
  }
  // --- inter: o += qf . kv_ex ---
#pragma unroll
  for (int kk = 0; kk < 4; ++kk) {
    const int krd = kk * 32 + lg * 8;
    short8 aF[4], bF[4];
#pragma unroll
    for (int i = 0; i < 4; ++i)
      aF[i] = *(const short8*)&sQ[(wr + i * 16 + l15) * LD + krd];
#pragma unroll
    for (int j = 0; j < 4; ++j)
      bF[j] = *(const short8*)&sKV[(wc + j * 16 + l15) * LD + krd];
#pragma unroll
    for (int i = 0; i < 4; ++i)
#pragma unroll
      for (int j = 0; j < 4; ++j)
        o[i][j] = MFMA16(aF[i], bF[j], o[i][j], 0, 0, 0);
  }

  // --- normalize + store y ---
#pragma unroll
  for (int i = 0; i < 4; ++i) {
    const int c0 = wr + i * 16 + lg * 4;
#pragma unroll
    for (int j = 0; j < 4; ++j) {
      const int e = wc + j * 16 + l15;
#pragma unroll
      for (int r = 0; r < 4; ++r) {
        const int c = c0 + r;
        const float zz = zpart[0][c] + zpart[1][c] + EPSf;
        Y[rowbase + (size_t)c * HID + e] = f2b(o[i][j][r] / zz);
      }
    }
  }
}

// ---------------------------------------------------------------------------
extern "C" void kernel_launch(void* const* d_in, const int* in_sizes, int n_in,
                              void* d_out, int out_size, void* d_ws, size_t ws_size,
                              hipStream_t stream)
{
  const float* x  = (const float*)d_in[0];
  const float* Wq = (const float*)d_in[1];
  const float* bq = (const float*)d_in[2];
  const float* Wk = (const float*)d_in[3];
  const float* bk = (const float*)d_in[4];
  const float* Wv = (const float*)d_in[5];
  const float* bv = (const float*)d_in[6];
  const float* Wo = (const float*)d_in[7];
  const float* bo = (const float*)d_in[8];
  float* out = (float*)d_out;

  char* p = (char*)d_ws;
  auto take = [&](size_t bytes) { char* q = p; p += (bytes + 255) & ~(size_t)255; return q; };
  u16* WqT = (u16*)take((size_t)HID * HID * 2);
  u16* WkT = (u16*)take((size_t)HID * HID * 2);
  u16* WvT = (u16*)take((size_t)HID * HID * 2);
  u16* WoT = (u16*)take((size_t)HID * HID * 2);
  u16* QF  = (u16*)take((size_t)Bsz * Ssz * HID * 2);   // later aliased as Y
  u16* KFb = (u16*)take((size_t)Bsz * Ssz * HID * 2);
  u16* Vb  = (u16*)take((size_t)Bsz * Ssz * HID * 2);
  // xb (bf16 x) aliases KVT: xb is dead once the QKV GEMM finishes.
  char* region = take((size_t)Bsz * Ssz * HID * 2);
  u16* xb  = (u16*)region;
  u16* KVT = (u16*)region;                               // 33.5 MB shared
  float* KS = (float*)take((size_t)Bsz * NCh * Hn * Dh * 4);
  u16* Yb = QF;   // safe alias: pass2 stages QF rows into LDS before writing Y

  // 128 KiB dynamic LDS for the GEMM (host-side attr set; capture-safe)
  (void)hipFuncSetAttribute((const void*)gemm4b<0>,
                            hipFuncAttributeMaxDynamicSharedMemorySize, 131072);
  (void)hipFuncSetAttribute((const void*)gemm4b<1>,
                            hipFuncAttributeMaxDynamicSharedMemorySize, 131072);

  dim3 blk(256, 1, 1);
  cvt_bf16<<<dim3(2048), blk, 0, stream>>>(x, xb);
  transpose4<<<dim3(HID / 64, HID / 64, 4), blk, 0, stream>>>(
      Wq, Wk, Wv, Wo, WqT, WkT, WvT, WoT);
  gemm4b<0><<<dim3(HID / 256, (Bsz * Ssz) / 256, 3), dim3(512), 131072, stream>>>(
      xb, WqT, WkT, WvT, bq, bk, bv, QF, KFb, Vb, 0x3);
  pass1_kv<<<dim3(Bsz * NCh * Hn), blk, 0, stream>>>(KFb, Vb, KVT, KS);
  cumsum_all<<<dim3((Bsz * Hn * Dh * Dh) / 256 + (Bsz * Hn * Dh) / 256), blk, 0, stream>>>(KVT, KS);
  pass2_attn<<<dim3(Bsz * NCh * Hn), blk, 0, stream>>>(QF, KFb, Vb, KVT, KS, Yb);
  gemm4b<1><<<dim3(HID / 256, (Bsz * Ssz) / 256, 1), dim3(512), 131072, stream>>>(
      Yb, WoT, WoT, WoT, bo, bo, bo, out, out, out, 0);
}